// Round 7
// baseline (372.511 us; speedup 1.0000x reference)
//
#include <hip/hip_runtime.h>
#include <math.h>

// B=4, N=4096, M=16384, Eg=65536, Ea=65536, D=512, DK=64
#define BB 4
#define NT 4096
#define ME 16384
#define EG 65536
#define EA 65536
#define DD 512
#define DKK 64

using bf16x8 = __attribute__((ext_vector_type(8))) short;
using f32x4  = __attribute__((ext_vector_type(4))) float;

static __device__ __forceinline__ unsigned short f2bf(float f) {
    unsigned u = __float_as_uint(f);
    u += 0x7fffu + ((u >> 16) & 1u);
    return (unsigned short)(u >> 16);
}
static __device__ __forceinline__ float bf2f(unsigned short u) {
    return __uint_as_float((unsigned)u << 16);
}
static __device__ __forceinline__ void acc8(float* a, uint4 v, float s) {
    a[0] += s * __uint_as_float(v.x << 16);
    a[1] += s * __uint_as_float(v.x & 0xffff0000u);
    a[2] += s * __uint_as_float(v.y << 16);
    a[3] += s * __uint_as_float(v.y & 0xffff0000u);
    a[4] += s * __uint_as_float(v.z << 16);
    a[5] += s * __uint_as_float(v.z & 0xffff0000u);
    a[6] += s * __uint_as_float(v.w << 16);
    a[7] += s * __uint_as_float(v.w & 0xffff0000u);
}
static __device__ __forceinline__ uint4 pack8(const float* a) {
    uint4 o;
    o.x = (unsigned)f2bf(a[0]) | ((unsigned)f2bf(a[1]) << 16);
    o.y = (unsigned)f2bf(a[2]) | ((unsigned)f2bf(a[3]) << 16);
    o.z = (unsigned)f2bf(a[4]) | ((unsigned)f2bf(a[5]) << 16);
    o.w = (unsigned)f2bf(a[6]) | ((unsigned)f2bf(a[7]) << 16);
    return o;
}

// ---------------- batched CSR build ----------------
__global__ void k_hist2(const int* __restrict__ ei_all, const int* __restrict__ ed_all,
                        int* __restrict__ cntG, int* __restrict__ cntA) {
    int i = blockIdx.x * 256 + threadIdx.x;
    if (i < BB * EG) {
        int b = i >> 16, e = i & (EG - 1);
        int dst = ei_all[(size_t)b * 2 * EG + EG + e];
        atomicAdd(&cntG[b * ME + dst], 1);
    } else {
        int j = i - BB * EG;
        atomicAdd(&cntA[(j >> 16) * NT + ed_all[j]], 1);
    }
}

__global__ __launch_bounds__(1024) void k_scan2(
    const int* __restrict__ cntG, int* __restrict__ offsG, int* __restrict__ curG,
    float* __restrict__ dinv,
    const int* __restrict__ cntA, int* __restrict__ offsA, int* __restrict__ curA) {
    __shared__ int sums[1024];
    int tid = threadIdx.x;
    int bid = blockIdx.x;
    const int* cnt;
    int *offs, *cur;
    float* dv = nullptr;
    int C, nk;
    if (bid < BB) {
        cnt = cntG + bid * ME; offs = offsG + bid * (ME + 1); cur = curG + bid * ME;
        dv = dinv + bid * ME; C = ME / 1024; nk = ME;
    } else {
        int b = bid - BB;
        cnt = cntA + b * NT; offs = offsA + b * (NT + 1); cur = curA + b * NT;
        C = NT / 1024; nk = NT;
    }
    int local[16];
    int tot = 0;
    for (int i = 0; i < C; ++i) { local[i] = cnt[tid * C + i]; tot += local[i]; }
    sums[tid] = tot;
    __syncthreads();
    for (int d = 1; d < 1024; d <<= 1) {
        int v = (tid >= d) ? sums[tid - d] : 0;
        __syncthreads();
        sums[tid] += v;
        __syncthreads();
    }
    int run = sums[tid] - tot;
    for (int i = 0; i < C; ++i) {
        int idx = tid * C + i;
        offs[idx] = run;
        cur[idx] = run;
        if (dv) dv[idx] = rsqrtf((float)local[i] + 1.0f);  // +1 self loop
        run += local[i];
    }
    if (tid == 1023) offs[nk] = run;
}

// CSR-direct fill: graph slots hold (token_row, dinv-bits); attention slots hold (src, dst)
__global__ void k_fill2(const int* __restrict__ ei_all, const int* __restrict__ es_all,
                        const int* __restrict__ ed_all, const int* __restrict__ t2e_all,
                        const float* __restrict__ dinv,
                        int* __restrict__ curG, int2* __restrict__ csrG,
                        int* __restrict__ curA, int2* __restrict__ csrA) {
    int i = blockIdx.x * 256 + threadIdx.x;
    if (i < BB * EG) {
        int b = i >> 16, e = i & (EG - 1);
        const int* ei = ei_all + (size_t)b * 2 * EG;
        int s = ei[e], d = ei[EG + e];
        int p = atomicAdd(&curG[b * ME + d], 1);
        int2 v;
        v.x = t2e_all[(b << 14) + s];
        v.y = __float_as_int(dinv[b * ME + s]);
        csrG[(size_t)b * EG + p] = v;
    } else {
        int j = i - BB * EG;
        int b = j >> 16;
        int p = atomicAdd(&curA[b * NT + ed_all[j]], 1);
        int2 v;
        v.x = es_all[j];
        v.y = ed_all[j];
        csrA[(size_t)b * EA + p] = v;
    }
}

// ---------------- casts / weight prep ----------------
__global__ void k_cast(const float* __restrict__ x, unsigned short* __restrict__ xb) {
    long i = (long)blockIdx.x * blockDim.x + threadIdx.x;
    float4 v = *(const float4*)(x + (i << 2));
    ushort4 o;
    o.x = f2bf(v.x); o.y = f2bf(v.y); o.z = f2bf(v.z); o.w = f2bf(v.w);
    *(ushort4*)(xb + (i << 2)) = o;
}

// combined transpose prep:
// i < 640*512 -> BtT[640][512] (rows 0..511 = Wgnn^T; 512..575 = Wgk^T; 576..639 = Wq^T)
// else        -> Wlt[512][512] = Wl^T
__global__ void k_wtT(const float* __restrict__ Wgnn, const float* __restrict__ Wgk,
                      const float* __restrict__ Wq, const float* __restrict__ Wl,
                      unsigned short* __restrict__ BtT, unsigned short* __restrict__ Wlt) {
    int i = blockIdx.x * 256 + threadIdx.x;  // [0, 1152*512)
    if (i < 640 * 512) {
        int n = i >> 9, k = i & 511;
        float v;
        if (n < 512)      v = Wgnn[((long)k << 9) + n];
        else if (n < 576) v = Wgk[k * 64 + (n - 512)];
        else              v = Wq[k * 64 + (n - 576)];
        BtT[i] = f2bf(v);
    } else {
        int j = i - 640 * 512;
        int n = j >> 9, k = j & 511;
        Wlt[j] = f2bf(Wl[((long)k << 9) + n]);
    }
}

// parallel bias prep: blocks 0..2 copy/zero; blocks 3..66 reduce bgk[n]
// biasG[576] = [bgnn | bgk], bgk[n]=bk[n]+sum bgnn[k]Wk[k][n]; bias640 = [0..0 | bq]
__global__ __launch_bounds__(256) void k_bias(
    const float* __restrict__ bgnn, const float* __restrict__ Wk,
    const float* __restrict__ bk, const float* __restrict__ bq,
    float* __restrict__ biasG, float* __restrict__ bias640) {
    int bx = blockIdx.x, tid = threadIdx.x;
    if (bx < 3) {
        int i = bx * 256 + tid;
        if (i < 512) { biasG[i] = bgnn[i]; bias640[i] = 0.0f; }
        else if (i < 576) { bias640[i] = 0.0f; }
        else if (i < 640) { bias640[i] = bq[i - 576]; }
        return;
    }
    int n = bx - 3;  // [0,64)
    __shared__ float red[256];
    float s = 0.0f;
    for (int k = tid; k < DD; k += 256) s += bgnn[k] * Wk[k * 64 + n];
    red[tid] = s;
    __syncthreads();
    for (int d = 128; d > 0; d >>= 1) {
        if (tid < d) red[tid] += red[tid + d];
        __syncthreads();
    }
    if (tid == 0) biasG[512 + n] = red[0] + bk[n];
}

// ---------------- token GEMM: X[B*NT,640] = tb @ [Wgnn|Wgk|Wq]^T + bias640 ----------------
__global__ __launch_bounds__(256, 2) void gemm_token(
    const unsigned short* __restrict__ A, const unsigned short* __restrict__ BtT,
    const float* __restrict__ bias640, unsigned short* __restrict__ Xg,
    unsigned short* __restrict__ Xk, unsigned short* __restrict__ qmatb)
{
    __shared__ short As[64 * 32];     // 4 KB
    __shared__ short Bs[320 * 32];    // 20 KB
    int tid = threadIdx.x;
    int lane = tid & 63;
    int w = tid >> 6;
    long bm = (long)blockIdx.x * 64;
    int bcol = blockIdx.y * 320;
    const unsigned short* Bblk = BtT + (long)bcol * DD;

    f32x4 acc[4][5] = {};

    for (int k0 = 0; k0 < DD; k0 += 32) {
        {
            int s = tid;
            int r = s >> 2;
            int gc = ((s & 3) ^ ((s >> 3) & 3)) * 8;
            __builtin_amdgcn_global_load_lds(
                (const __attribute__((address_space(1))) unsigned int*)(A + (bm + r) * DD + k0 + gc),
                (__attribute__((address_space(3))) unsigned int*)(As + s * 8), 16, 0, 0);
        }
#pragma unroll
        for (int i = 0; i < 5; ++i) {
            int s = tid + i * 256;
            int r = s >> 2;
            int gc = ((s & 3) ^ ((s >> 3) & 3)) * 8;
            __builtin_amdgcn_global_load_lds(
                (const __attribute__((address_space(1))) unsigned int*)(Bblk + (long)r * DD + k0 + gc),
                (__attribute__((address_space(3))) unsigned int*)(Bs + s * 8), 16, 0, 0);
        }
        __syncthreads();

        int cq = lane >> 4;
        bf16x8 af[4];
#pragma unroll
        for (int rb = 0; rb < 4; ++rb) {
            int r = rb * 16 + (lane & 15);
            af[rb] = *(const bf16x8*)&As[(r * 4 + (cq ^ ((r >> 1) & 3))) * 8];
        }
#pragma unroll
        for (int cb = 0; cb < 5; ++cb) {
            int r = w * 80 + cb * 16 + (lane & 15);
            bf16x8 bf = *(const bf16x8*)&Bs[(r * 4 + (cq ^ ((r >> 1) & 3))) * 8];
#pragma unroll
            for (int rb = 0; rb < 4; ++rb)
                acc[rb][cb] = __builtin_amdgcn_mfma_f32_16x16x32_bf16(af[rb], bf, acc[rb][cb], 0, 0, 0);
        }
        __syncthreads();
    }

#pragma unroll
    for (int rb = 0; rb < 4; ++rb) {
        long row0 = bm + rb * 16 + ((lane >> 4) << 2);
#pragma unroll
        for (int cb = 0; cb < 5; ++cb) {
            int col = bcol + w * 80 + cb * 16 + (lane & 15);
            float bv = bias640[col];
            if (col < 512) {
#pragma unroll
                for (int r = 0; r < 4; ++r)
                    Xg[(row0 + r) * DD + col] = f2bf(acc[rb][cb][r] + bv);
            } else if (col < 576) {
#pragma unroll
                for (int r = 0; r < 4; ++r)
                    Xk[(row0 + r) * DKK + (col - 512)] = f2bf(acc[rb][cb][r] + bv);
            } else {
#pragma unroll
                for (int r = 0; r < 4; ++r)
                    qmatb[(row0 + r) * DKK + (col - 576)] = f2bf(acc[rb][cb][r] + bv);
            }
        }
    }
}

// ---------------- GCN aggregation: one wave per (b,m), 4-deep main + clamped-4 tail ----------------
// XCD-batch swizzle: blocks of batch b land on XCDs {2b, 2b+1} (blockIdx%8 round-robin),
// so each XCD's L2 holds only that batch's Xg+Xk (~4.7 MB).
__global__ __launch_bounds__(256) void k_gcn_gather(
    const unsigned short* __restrict__ Xg, const unsigned short* __restrict__ Xk,
    const int* __restrict__ t2e_all, const float* __restrict__ dinv,
    const int* __restrict__ offsG, const int2* __restrict__ csrG,
    const float* __restrict__ biasG,
    unsigned short* __restrict__ eeb, unsigned short* __restrict__ kmatb)
{
    int w = threadIdx.x >> 6;
    int lane = threadIdx.x & 63;
    int bx = blockIdx.x;                   // [0, 16384)
    int b = (bx & 7) >> 1;                 // batch -> XCD pair
    int half = bx & 1;
    int idx = bx >> 3;                     // [0, 2048)
    int m = (half * 2048 + idx) * 4 + w;   // [0, 16384)
    int mg = (b << 14) + m;
    const int* offs = offsG + b * (ME + 1);
    const int2* csr = csrG + (size_t)b * EG;
    const unsigned short* gl = Xg + (((long)b * NT) << 9) + lane * 8;
    const unsigned short* kl = Xk + ((long)b * NT) * DKK + lane;

    float dm = dinv[mg];
    int self = t2e_all[mg];
    uint4 vself = *(const uint4*)(gl + ((long)self << 9));
    float kself = bf2f(kl[(long)self * DKK]);

    float a[8] = {0, 0, 0, 0, 0, 0, 0, 0};
    float ak = 0.0f;
    int p = offs[m], end = offs[m + 1];
    for (; p + 4 <= end; p += 4) {
        int2 e0 = csr[p], e1 = csr[p + 1], e2 = csr[p + 2], e3 = csr[p + 3];
        uint4 r0 = *(const uint4*)(gl + ((long)e0.x << 9));
        uint4 r1 = *(const uint4*)(gl + ((long)e1.x << 9));
        uint4 r2 = *(const uint4*)(gl + ((long)e2.x << 9));
        uint4 r3 = *(const uint4*)(gl + ((long)e3.x << 9));
        float k0 = bf2f(kl[(long)e0.x * DKK]);
        float k1 = bf2f(kl[(long)e1.x * DKK]);
        float k2 = bf2f(kl[(long)e2.x * DKK]);
        float k3 = bf2f(kl[(long)e3.x * DKK]);
        float w0 = __int_as_float(e0.y), w1 = __int_as_float(e1.y);
        float w2 = __int_as_float(e2.y), w3 = __int_as_float(e3.y);
        acc8(a, r0, w0); ak += w0 * k0;
        acc8(a, r1, w1); ak += w1 * k1;
        acc8(a, r2, w2); ak += w2 * k2;
        acc8(a, r3, w3); ak += w3 * k3;
    }
    if (p < end) {
        // branch-free clamped tail: keeps 4 loads in flight, zero-weights the pad slots
        int e1m = end - 1;
        int i1 = min(p + 1, e1m), i2 = min(p + 2, e1m), i3 = min(p + 3, e1m);
        int2 e0 = csr[p], e1 = csr[i1], e2 = csr[i2], e3 = csr[i3];
        uint4 r0 = *(const uint4*)(gl + ((long)e0.x << 9));
        uint4 r1 = *(const uint4*)(gl + ((long)e1.x << 9));
        uint4 r2 = *(const uint4*)(gl + ((long)e2.x << 9));
        uint4 r3 = *(const uint4*)(gl + ((long)e3.x << 9));
        float k0 = bf2f(kl[(long)e0.x * DKK]);
        float k1 = bf2f(kl[(long)e1.x * DKK]);
        float k2 = bf2f(kl[(long)e2.x * DKK]);
        float k3 = bf2f(kl[(long)e3.x * DKK]);
        float w0 = __int_as_float(e0.y);
        float w1 = (p + 1 < end) ? __int_as_float(e1.y) : 0.0f;
        float w2 = (p + 2 < end) ? __int_as_float(e2.y) : 0.0f;
        float w3 = (p + 3 < end) ? __int_as_float(e3.y) : 0.0f;
        acc8(a, r0, w0); ak += w0 * k0;
        acc8(a, r1, w1); ak += w1 * k1;
        acc8(a, r2, w2); ak += w2 * k2;
        acc8(a, r3, w3); ak += w3 * k3;
    }
    acc8(a, vself, dm);
    ak += dm * kself;

    const float* bg = biasG + lane * 8;
    float4 b0 = *(const float4*)bg;
    float4 b1 = *(const float4*)(bg + 4);
    a[0] = dm * a[0] + b0.x; a[1] = dm * a[1] + b0.y;
    a[2] = dm * a[2] + b0.z; a[3] = dm * a[3] + b0.w;
    a[4] = dm * a[4] + b1.x; a[5] = dm * a[5] + b1.y;
    a[6] = dm * a[6] + b1.z; a[7] = dm * a[7] + b1.w;
    *(uint4*)(eeb + ((long)mg << 9) + lane * 8) = pack8(a);
    kmatb[(long)mg * DKK + lane] = f2bf(dm * ak + biasG[512 + lane]);
}

// ---------------- attention dots: one thread per CSR position, XCD-batch swizzle ----------------
// writes fused (src, exp-weight-bits) stream so the gather loop issues ONE 8B load per edge
__global__ void k_dots(const unsigned short* __restrict__ kmatb,
                       const unsigned short* __restrict__ qmatb,
                       const int2* __restrict__ csrA, int2* __restrict__ swbuf) {
    int bx = blockIdx.x;                   // [0, 1024)
    int b = (bx & 7) >> 1;                 // batch -> XCD pair (kmatb+qmatb L2-resident)
    int half = bx & 1;
    int idx = bx >> 3;                     // [0, 128)
    int p = (b << 16) + (half * 128 + idx) * 256 + threadIdx.x;
    int2 sd = csrA[p];
    const uint4* kr = (const uint4*)(kmatb + ((long)(b * ME + sd.x) << 6));
    const uint4* qr = (const uint4*)(qmatb + ((long)(b * NT + sd.y) << 6));
    float dot = 0.0f;
#pragma unroll
    for (int j = 0; j < 8; ++j) {
        uint4 kv = kr[j];
        uint4 qv = qr[j];
        dot += __uint_as_float(kv.x << 16) * __uint_as_float(qv.x << 16)
             + __uint_as_float(kv.x & 0xffff0000u) * __uint_as_float(qv.x & 0xffff0000u)
             + __uint_as_float(kv.y << 16) * __uint_as_float(qv.y << 16)
             + __uint_as_float(kv.y & 0xffff0000u) * __uint_as_float(qv.y & 0xffff0000u)
             + __uint_as_float(kv.z << 16) * __uint_as_float(qv.z << 16)
             + __uint_as_float(kv.z & 0xffff0000u) * __uint_as_float(qv.z & 0xffff0000u)
             + __uint_as_float(kv.w << 16) * __uint_as_float(qv.w << 16)
             + __uint_as_float(kv.w & 0xffff0000u) * __uint_as_float(qv.w & 0xffff0000u);
    }
    int2 o;
    o.x = sd.x;
    o.y = __float_as_int(expf(dot * 0.125f));  // /sqrt(64); softmax max-shift is exact no-op
    swbuf[p] = o;
}

// ---------------- attention aggregation: one wave per (b,n), 8-deep ILP ----------------
// XCD-batch swizzle: batch b -> XCDs {2b,2b+1}; each XCD pair's L2 (8 MB) then serves only
// that batch's eeb (16.8 MB) -> random re-reads ~50% L2-hit instead of ~6%.
__global__ __launch_bounds__(256) void k_att_gather(
    const unsigned short* __restrict__ eeb, const int2* __restrict__ swbuf,
    const int* __restrict__ offsA,
    const float* __restrict__ t_all, const float* __restrict__ ga,
    float* __restrict__ out, unsigned short* __restrict__ nb)
{
    int w = threadIdx.x >> 6;
    int lane = threadIdx.x & 63;
    int bx = blockIdx.x;                   // [0, 4096)
    int b = (bx & 7) >> 1;                 // batch -> XCD pair
    int half = bx & 1;
    int idx = bx >> 3;                     // [0, 512)
    int n = (half * 512 + idx) * 4 + w;    // [0, 4096)
    int ng = (b << 12) + n;
    const int* offs = offsA + b * (NT + 1);
    const int2* swb = swbuf + (size_t)b * EA;
    const unsigned short* el = eeb + (((size_t)b * ME) << 9) + lane * 8;

    float a[8] = {0, 0, 0, 0, 0, 0, 0, 0};
    float den = 0.0f;
    int p = offs[n], end = offs[n + 1];
    for (; p + 8 <= end; p += 8) {
        int2 e0 = swb[p],     e1 = swb[p + 1], e2 = swb[p + 2], e3 = swb[p + 3];
        int2 e4 = swb[p + 4], e5 = swb[p + 5], e6 = swb[p + 6], e7 = swb[p + 7];
        uint4 r0 = *(const uint4*)(el + ((long)e0.x << 9));
        uint4 r1 = *(const uint4*)(el + ((long)e1.x << 9));
        uint4 r2 = *(const uint4*)(el + ((long)e2.x << 9));
        uint4 r3 = *(const uint4*)(el + ((long)e3.x << 9));
        uint4 r4 = *(const uint4*)(el + ((long)e4.x << 9));
        uint4 r5 = *(const uint4*)(el + ((long)e5.x << 9));
        uint4 r6 = *(const uint4*)(el + ((long)e6.x << 9));
        uint4 r7 = *(const uint4*)(el + ((long)e7.x << 9));
        float w0 = __int_as_float(e0.y), w1 = __int_as_float(e1.y);
        float w2 = __int_as_float(e2.y), w3 = __int_as_float(e3.y);
        float w4 = __int_as_float(e4.y), w5 = __int_as_float(e5.y);
        float w6 = __int_as_float(e6.y), w7 = __int_as_float(e7.y);
        den += (w0 + w1 + w2 + w3) + (w4 + w5 + w6 + w7);
        acc8(a, r0, w0);
        acc8(a, r1, w1);
        acc8(a, r2, w2);
        acc8(a, r3, w3);
        acc8(a, r4, w4);
        acc8(a, r5, w5);
        acc8(a, r6, w6);
        acc8(a, r7, w7);
    }
    if (p < end) {
        // branch-free clamped tail: pad slots re-read row end-1 (L1 hit) with weight 0
        int e1m = end - 1;
        int2 e0 = swb[p];
        int2 e1 = swb[min(p + 1, e1m)];
        int2 e2 = swb[min(p + 2, e1m)];
        int2 e3 = swb[min(p + 3, e1m)];
        int2 e4 = swb[min(p + 4, e1m)];
        int2 e5 = swb[min(p + 5, e1m)];
        int2 e6 = swb[min(p + 6, e1m)];
        int2 e7 = swb[min(p + 7, e1m)];
        uint4 r0 = *(const uint4*)(el + ((long)e0.x << 9));
        uint4 r1 = *(const uint4*)(el + ((long)e1.x << 9));
        uint4 r2 = *(const uint4*)(el + ((long)e2.x << 9));
        uint4 r3 = *(const uint4*)(el + ((long)e3.x << 9));
        uint4 r4 = *(const uint4*)(el + ((long)e4.x << 9));
        uint4 r5 = *(const uint4*)(el + ((long)e5.x << 9));
        uint4 r6 = *(const uint4*)(el + ((long)e6.x << 9));
        uint4 r7 = *(const uint4*)(el + ((long)e7.x << 9));
        float w0 = __int_as_float(e0.y);
        float w1 = (p + 1 < end) ? __int_as_float(e1.y) : 0.0f;
        float w2 = (p + 2 < end) ? __int_as_float(e2.y) : 0.0f;
        float w3 = (p + 3 < end) ? __int_as_float(e3.y) : 0.0f;
        float w4 = (p + 4 < end) ? __int_as_float(e4.y) : 0.0f;
        float w5 = (p + 5 < end) ? __int_as_float(e5.y) : 0.0f;
        float w6 = (p + 6 < end) ? __int_as_float(e6.y) : 0.0f;
        float w7 = (p + 7 < end) ? __int_as_float(e7.y) : 0.0f;
        den += (w0 + w1 + w2 + w3) + (w4 + w5 + w6 + w7);
        acc8(a, r0, w0);
        acc8(a, r1, w1);
        acc8(a, r2, w2);
        acc8(a, r3, w3);
        acc8(a, r4, w4);
        acc8(a, r5, w5);
        acc8(a, r6, w6);
        acc8(a, r7, w7);
    }
    float g = tanhf(ga[0]);
    float inv = den > 0.0f ? g / den : 0.0f;
    const float* tr = t_all + ((long)ng << 9) + lane * 8;
    float4 t0 = *(const float4*)tr;
    float4 t1 = *(const float4*)(tr + 4);
    float o[8];
    o[0] = t0.x + inv * a[0]; o[1] = t0.y + inv * a[1];
    o[2] = t0.z + inv * a[2]; o[3] = t0.w + inv * a[3];
    o[4] = t1.x + inv * a[4]; o[5] = t1.y + inv * a[5];
    o[6] = t1.z + inv * a[6]; o[7] = t1.w + inv * a[7];
    float* op = out + ((long)ng << 9) + lane * 8;
    *(float4*)op = make_float4(o[0], o[1], o[2], o[3]);
    *(float4*)(op + 4) = make_float4(o[4], o[5], o[6], o[7]);
    *(uint4*)(nb + ((long)ng << 9) + lane * 8) = pack8(o);
}

// ---------------- final linear: 128-row x 256-col blocks, XOR-swizzled LDS ----------------
// Cf += tanh(gs[0]) * (A @ Bt^T + bias)
__global__ __launch_bounds__(256, 2) void gemm_final(
    const unsigned short* __restrict__ A, const unsigned short* __restrict__ Bt,
    const float* __restrict__ bias, float* __restrict__ Cf, const float* __restrict__ gs)
{
    constexpr int CB = 8;
    constexpr int BROWS = 2 * CB * 16;      // 256
    __shared__ short As[128 * 32];
    __shared__ short Bs[BROWS * 32];
    int tid = threadIdx.x;
    int lane = tid & 63;
    int w = tid >> 6;
    int wm = w >> 1, wn = w & 1;
    long bm = (long)blockIdx.x * 128;
    int bcol = blockIdx.y * BROWS;
    const unsigned short* Bblk = Bt + (long)bcol * DD;

    f32x4 acc[4][CB] = {};

    for (int k0 = 0; k0 < DD; k0 += 32) {
#pragma unroll
        for (int i = 0; i < 2; ++i) {
            int s = tid + i * 256;
            int r = s >> 2;
            int gc = ((s & 3) ^ ((s >> 3) & 3)) * 8;
            __builtin_amdgcn_global_load_lds(
                (const __attribute__((address_space(1))) unsigned int*)(A + (bm + r) * DD + k0 + gc),
                (__attribute__((address_space(3))) unsigned int*)(As + s * 8), 16, 0, 0);
        }
#pragma unroll
        for (int i = 0; i < CB / 2; ++i) {
            int s = tid + i * 256;
            int r = s >> 2;
            int gc = ((s & 3) ^ ((s >> 3) & 3)) * 8;
            __builtin_amdgcn_global_load_lds(
                (const __attribute__((address_space(1))) unsigned int*)(Bblk + (long)r * DD + k0 + gc),
                (__attribute__((address_space(3))) unsigned int*)(Bs + s * 8), 16, 0, 0);
        }
        __syncthreads();

        int cq = lane >> 4;
        bf16x8 af[4];
#pragma unroll
        for (int rb = 0; rb < 4; ++rb) {
            int r = wm * 64 + rb * 16 + (lane & 15);
            af[rb] = *(const bf16x8*)&As[(r * 4 + (cq ^ ((r >> 1) & 3))) * 8];
        }
#pragma unroll
        for (int cb = 0; cb < CB; ++cb) {
            int r = wn * (CB * 16) + cb * 16 + (lane & 15);
            bf16x8 bf = *(const bf16x8*)&Bs[(r * 4 + (cq ^ ((r >> 1) & 3))) * 8];
#pragma unroll
            for (int rb = 0; rb < 4; ++rb)
                acc[rb][cb] = __builtin_amdgcn_mfma_f32_16x16x32_bf16(af[rb], bf, acc[rb][cb], 0, 0, 0);
        }
        __syncthreads();
    }

    float g = tanhf(gs[0]);
#pragma unroll
    for (int rb = 0; rb < 4; ++rb) {
        long row0 = bm + wm * 64 + rb * 16 + ((lane >> 4) << 2);
#pragma unroll
        for (int cb = 0; cb < CB; ++cb) {
            int col = bcol + wn * (CB * 16) + cb * 16 + (lane & 15);
            float bv = bias[col];
#pragma unroll
            for (int r = 0; r < 4; ++r)
                Cf[(row0 + r) * DD + col] += g * (acc[rb][cb][r] + bv);
        }
    }
}

// ---------------- fp32 tiled GEMM (one-time Wgk = Wgnn @ Wk) ----------------
__global__ void gemm_tiled(const float* __restrict__ A, const float* __restrict__ Bw,
                           float* __restrict__ C, int K, int Nc) {
    __shared__ float As[16][64];
    __shared__ float Bs[16][64];
    int tid = threadIdx.x;
    int tx = tid & 15, ty = tid >> 4;
    int bm = blockIdx.x * 64, bn = blockIdx.y * 64;
    float acc[4][4] = {};
    int arow = bm + (tid >> 2);
    long aoff = (long)arow * K;
    int kk0 = (tid & 3) * 4;
    int arowl = tid >> 2;
    for (int k0 = 0; k0 < K; k0 += 16) {
        float4 av = *(const float4*)(A + aoff + k0 + kk0);
        As[kk0 + 0][arowl] = av.x;
        As[kk0 + 1][arowl] = av.y;
        As[kk0 + 2][arowl] = av.z;
        As[kk0 + 3][arowl] = av.w;
        float4 bv = *(const float4*)(Bw + (long)(k0 + (tid >> 4)) * Nc + bn + (tid & 15) * 4);
        *(float4*)&Bs[tid >> 4][(tid & 15) * 4] = bv;
        __syncthreads();
#pragma unroll
        for (int k = 0; k < 16; ++k) {
            float4 a = *(const float4*)&As[k][ty * 4];
            float4 b = *(const float4*)&Bs[k][tx * 4];
            acc[0][0] += a.x * b.x; acc[0][1] += a.x * b.y; acc[0][2] += a.x * b.z; acc[0][3] += a.x * b.w;
            acc[1][0] += a.y * b.x; acc[1][1] += a.y * b.y; acc[1][2] += a.y * b.z; acc[1][3] += a.y * b.w;
            acc[2][0] += a.z * b.x; acc[2][1] += a.z * b.y; acc[2][2] += a.z * b.z; acc[2][3] += a.z * b.w;
            acc[3][0] += a.w * b.x; acc[3][1] += a.w * b.y; acc[3][2] += a.w * b.z; acc[3][3] += a.w * b.w;
        }
        __syncthreads();
    }
#pragma unroll
    for (int i = 0; i < 4; ++i)
        *(float4*)(C + (long)(bm + ty * 4 + i) * Nc + bn + tx * 4) =
            make_float4(acc[i][0], acc[i][1], acc[i][2], acc[i][3]);
}

extern "C" void kernel_launch(void* const* d_in, const int* in_sizes, int n_in,
                              void* d_out, int out_size, void* d_ws, size_t ws_size,
                              hipStream_t stream) {
    const float* t_all   = (const float*)d_in[0];
    const int*   t2e_all = (const int*)d_in[1];
    const int*   ei_all  = (const int*)d_in[2];
    const int*   es_all  = (const int*)d_in[3];
    const int*   ed_all  = (const int*)d_in[4];
    const float* Wgnn    = (const float*)d_in[5];
    const float* bgnn    = (const float*)d_in[6];
    const float* Wk      = (const float*)d_in[7];
    const float* bk      = (const float*)d_in[8];
    const float* Wq      = (const float*)d_in[9];
    const float* bq      = (const float*)d_in[10];
    const float* Wl      = (const float*)d_in[11];
    const float* bl      = (const float*)d_in[12];
    const float* ga      = (const float*)d_in[13];
    const float* gb      = (const float*)d_in[14];
    float* out = (float*)d_out;

    // workspace (~145 MB of 256 MiB)
    char* wsb = (char*)d_ws;
    size_t off = 0;
    unsigned short* eeb   = (unsigned short*)(wsb + off); off += (size_t)BB * ME * DD * 2;  // 67.1 MB
    unsigned short* tb    = (unsigned short*)(wsb + off); off += (size_t)BB * NT * DD * 2;  // 16.8 MB
    unsigned short* Xg    = (unsigned short*)(wsb + off); off += (size_t)BB * NT * DD * 2;  // 16.8 MB
    unsigned short* nb    = (unsigned short*)(wsb + off); off += (size_t)BB * NT * DD * 2;  // 16.8 MB
    unsigned short* Xk    = (unsigned short*)(wsb + off); off += (size_t)BB * NT * DKK * 2; // 2.1 MB
    unsigned short* qmatb = (unsigned short*)(wsb + off); off += (size_t)BB * NT * DKK * 2; // 2.1 MB
    unsigned short* kmatb = (unsigned short*)(wsb + off); off += (size_t)BB * ME * DKK * 2; // 8.4 MB
    unsigned short* BtT   = (unsigned short*)(wsb + off); off += (size_t)640 * DD * 2;
    unsigned short* Wlt   = (unsigned short*)(wsb + off); off += (size_t)DD * DD * 2;
    float* Wgk     = (float*)(wsb + off); off += (size_t)DD * DKK * 4;
    float* biasG   = (float*)(wsb + off); off += 576 * 4;
    float* bias640 = (float*)(wsb + off); off += 640 * 4;
    float* dinv  = (float*)(wsb + off); off += (size_t)BB * ME * 4;
    int2* swbuf  = (int2*)(wsb + off); off += (size_t)BB * EA * 8;   // fused (src, exp-weight)
    int* cntG  = (int*)(wsb + off); off += (size_t)BB * ME * 4;   // cntG+cntA contiguous
    int* cntA  = (int*)(wsb + off); off += (size_t)BB * NT * 4;
    int* offsG = (int*)(wsb + off); off += (size_t)BB * (ME + 1) * 4;
    int* curG  = (int*)(wsb + off); off += (size_t)BB * ME * 4;
    int2* csrG = (int2*)(wsb + off); off += (size_t)BB * EG * 8;
    int* offsA = (int*)(wsb + off); off += (size_t)BB * (NT + 1) * 4;
    int* curA  = (int*)(wsb + off); off += (size_t)BB * NT * 4;
    int2* csrA = (int2*)(wsb + off); off += (size_t)BB * EA * 8;

    // ---- one-time weight prep ----
    gemm_tiled<<<dim3(DD / 64, 1), 256, 0, stream>>>(Wgnn, Wk, Wgk, DD, DKK);  // Wgk = Wgnn@Wk
    k_wtT<<<(1152 * DD) / 256, 256, 0, stream>>>(Wgnn, Wgk, Wq, Wl, BtT, Wlt);
    k_bias<<<67, 256, 0, stream>>>(bgnn, Wk, bk, bq, biasG, bias640);

    // ---- batched CSR build ----
    hipMemsetAsync(cntG, 0, (size_t)BB * (ME + NT) * 4, stream);
    k_hist2<<<(BB * (EG + EA)) / 256, 256, 0, stream>>>(ei_all, ed_all, cntG, cntA);
    k_scan2<<<2 * BB, 1024, 0, stream>>>(cntG, offsG, curG, dinv, cntA, offsA, curA);
    k_fill2<<<(BB * (EG + EA)) / 256, 256, 0, stream>>>(
        ei_all, es_all, ed_all, t2e_all, dinv, curG, csrG, curA, csrA);

    // ---- bf16 tokens, then token projection X = tb @ [Wgnn|Wgk|Wq] (+bq on q cols) ----
    k_cast<<<(int)(((long)BB * NT * DD / 4) / 256), 256, 0, stream>>>(t_all, tb);
    gemm_token<<<dim3((BB * NT) / 64, 2), 256, 0, stream>>>(tb, BtT, bias640, Xg, Xk, qmatb);

    // ---- GCN aggregation in projected space -> eeb, kmatb directly ----
    k_gcn_gather<<<(BB * ME * 64) / 256, 256, 0, stream>>>(
        Xg, Xk, t2e_all, dinv, offsG, csrG, biasG, eeb, kmatb);

    // ---- attention ----
    k_dots<<<(BB * EA) / 256, 256, 0, stream>>>(kmatb, qmatb, csrA, swbuf);
    k_att_gather<<<(BB * NT * 64) / 256, 256, 0, stream>>>(
        eeb, swbuf, offsA, t_all, ga, out, nb);

    // ---- final: out += tanh(gb) * (nb @ Wl + bl) ----
    gemm_final<<<dim3((BB * NT) / 128, 2), 256, 0, stream>>>(nb, Wlt, bl, out, gb);
}

// Round 8
// 334.695 us; speedup vs baseline: 1.1130x; 1.1130x over previous
//
#include <hip/hip_runtime.h>
#include <math.h>

// B=4, N=4096, M=16384, Eg=65536, Ea=65536, D=512, DK=64
#define BB 4
#define NT 4096
#define ME 16384
#define EG 65536
#define EA 65536
#define DD 512
#define DKK 64

using bf16x8 = __attribute__((ext_vector_type(8))) short;
using f32x4  = __attribute__((ext_vector_type(4))) float;

static __device__ __forceinline__ unsigned short f2bf(float f) {
    unsigned u = __float_as_uint(f);
    u += 0x7fffu + ((u >> 16) & 1u);
    return (unsigned short)(u >> 16);
}
static __device__ __forceinline__ float bf2f(unsigned short u) {
    return __uint_as_float((unsigned)u << 16);
}
static __device__ __forceinline__ void acc8(float* a, uint4 v, float s) {
    a[0] += s * __uint_as_float(v.x << 16);
    a[1] += s * __uint_as_float(v.x & 0xffff0000u);
    a[2] += s * __uint_as_float(v.y << 16);
    a[3] += s * __uint_as_float(v.y & 0xffff0000u);
    a[4] += s * __uint_as_float(v.z << 16);
    a[5] += s * __uint_as_float(v.z & 0xffff0000u);
    a[6] += s * __uint_as_float(v.w << 16);
    a[7] += s * __uint_as_float(v.w & 0xffff0000u);
}
static __device__ __forceinline__ uint4 pack8(const float* a) {
    uint4 o;
    o.x = (unsigned)f2bf(a[0]) | ((unsigned)f2bf(a[1]) << 16);
    o.y = (unsigned)f2bf(a[2]) | ((unsigned)f2bf(a[3]) << 16);
    o.z = (unsigned)f2bf(a[4]) | ((unsigned)f2bf(a[5]) << 16);
    o.w = (unsigned)f2bf(a[6]) | ((unsigned)f2bf(a[7]) << 16);
    return o;
}

// ---------------- fused prep: wtT(fold) | bias | cast | hist ----------------
// blocks [0,2304): BtT/Wlt transpose prep (Wgk = Wgnn@Wk folded inline)
// blocks [2304,2371): bias prep
// blocks [2371,10563): t_all -> tb bf16 cast
// blocks [10563,12611): CSR histogram (cntG/cntA must be pre-zeroed)
#define PREP_WTT   2304
#define PREP_BIAS  (PREP_WTT + 67)
#define PREP_CAST  (PREP_BIAS + 8192)
#define PREP_HIST  (PREP_CAST + 2048)
__global__ __launch_bounds__(256) void k_prep(
    const float* __restrict__ Wgnn, const float* __restrict__ Wk,
    const float* __restrict__ Wq, const float* __restrict__ Wl,
    const float* __restrict__ bgnn, const float* __restrict__ bk,
    const float* __restrict__ bq, const float* __restrict__ t_all,
    const int* __restrict__ ei_all, const int* __restrict__ ed_all,
    unsigned short* __restrict__ BtT, unsigned short* __restrict__ Wlt,
    float* __restrict__ biasG, float* __restrict__ bias640,
    unsigned short* __restrict__ tb, int* __restrict__ cntG, int* __restrict__ cntA)
{
    __shared__ float red[256];
    int bx = blockIdx.x, tid = threadIdx.x;
    if (bx < PREP_WTT) {
        int i = bx * 256 + tid;  // [0, 1152*512)
        if (i < 640 * 512) {
            int n = i >> 9, k = i & 511;
            float v;
            if (n < 512)      v = Wgnn[((long)k << 9) + n];
            else if (n < 576) {
                int c = n - 512;
                const float* wr = Wgnn + ((long)k << 9);
                float s = 0.0f;
                for (int j = 0; j < DD; ++j) s += wr[j] * Wk[j * 64 + c];
                v = s;
            } else            v = Wq[k * 64 + (n - 576)];
            BtT[i] = f2bf(v);
        } else {
            int j = i - 640 * 512;
            int n = j >> 9, k = j & 511;
            Wlt[j] = f2bf(Wl[((long)k << 9) + n]);
        }
    } else if (bx < PREP_BIAS) {
        int bb = bx - PREP_WTT;
        if (bb < 3) {
            int i = bb * 256 + tid;
            if (i < 512) { biasG[i] = bgnn[i]; bias640[i] = 0.0f; }
            else if (i < 576) { bias640[i] = 0.0f; }
            else if (i < 640) { bias640[i] = bq[i - 576]; }
            return;
        }
        int n = bb - 3;  // [0,64)
        float s = 0.0f;
        for (int k = tid; k < DD; k += 256) s += bgnn[k] * Wk[k * 64 + n];
        red[tid] = s;
        __syncthreads();
        for (int d = 128; d > 0; d >>= 1) {
            if (tid < d) red[tid] += red[tid + d];
            __syncthreads();
        }
        if (tid == 0) biasG[512 + n] = red[0] + bk[n];
    } else if (bx < PREP_CAST) {
        long i = (long)(bx - PREP_BIAS) * 256 + tid;
        float4 v = *(const float4*)(t_all + (i << 2));
        ushort4 o;
        o.x = f2bf(v.x); o.y = f2bf(v.y); o.z = f2bf(v.z); o.w = f2bf(v.w);
        *(ushort4*)(tb + (i << 2)) = o;
    } else {
        int i = (bx - PREP_CAST) * 256 + tid;  // [0, BB*(EG+EA))
        if (i < BB * EG) {
            int b = i >> 16, e = i & (EG - 1);
            int dst = ei_all[(size_t)b * 2 * EG + EG + e];
            atomicAdd(&cntG[b * ME + dst], 1);
        } else {
            int j = i - BB * EG;
            atomicAdd(&cntA[(j >> 16) * NT + ed_all[j]], 1);
        }
    }
}

__global__ __launch_bounds__(1024) void k_scan2(
    const int* __restrict__ cntG, int* __restrict__ offsG, int* __restrict__ curG,
    float* __restrict__ dinv,
    const int* __restrict__ cntA, int* __restrict__ offsA, int* __restrict__ curA) {
    __shared__ int sums[1024];
    int tid = threadIdx.x;
    int bid = blockIdx.x;
    const int* cnt;
    int *offs, *cur;
    float* dv = nullptr;
    int C, nk;
    if (bid < BB) {
        cnt = cntG + bid * ME; offs = offsG + bid * (ME + 1); cur = curG + bid * ME;
        dv = dinv + bid * ME; C = ME / 1024; nk = ME;
    } else {
        int b = bid - BB;
        cnt = cntA + b * NT; offs = offsA + b * (NT + 1); cur = curA + b * NT;
        C = NT / 1024; nk = NT;
    }
    int local[16];
    int tot = 0;
    for (int i = 0; i < C; ++i) { local[i] = cnt[tid * C + i]; tot += local[i]; }
    sums[tid] = tot;
    __syncthreads();
    for (int d = 1; d < 1024; d <<= 1) {
        int v = (tid >= d) ? sums[tid - d] : 0;
        __syncthreads();
        sums[tid] += v;
        __syncthreads();
    }
    int run = sums[tid] - tot;
    for (int i = 0; i < C; ++i) {
        int idx = tid * C + i;
        offs[idx] = run;
        cur[idx] = run;
        if (dv) dv[idx] = rsqrtf((float)local[i] + 1.0f);  // +1 self loop
        run += local[i];
    }
    if (tid == 1023) offs[nk] = run;
}

// ---------------- fused: token GEMM [0,512) | CSR fill [512,2560) ----------------
// gemm: X[B*NT,640] = tb @ [Wgnn|Wgk|Wq]^T + bias640, 64-row x 320-col tiles
// fill: CSR-direct scatter (needs scan's cursors; overlaps with the GEMM blocks)
__global__ __launch_bounds__(256, 2) void k_fill_token(
    const int* __restrict__ ei_all, const int* __restrict__ es_all,
    const int* __restrict__ ed_all, const int* __restrict__ t2e_all,
    const float* __restrict__ dinv,
    int* __restrict__ curG, int2* __restrict__ csrG,
    int* __restrict__ curA, int2* __restrict__ csrA,
    const unsigned short* __restrict__ A, const unsigned short* __restrict__ BtT,
    const float* __restrict__ bias640, unsigned short* __restrict__ Xg,
    unsigned short* __restrict__ Xk, unsigned short* __restrict__ qmatb)
{
    __shared__ short As[64 * 32];     // 4 KB
    __shared__ short Bs[320 * 32];    // 20 KB
    int tid = threadIdx.x;
    int bxx = blockIdx.x;

    if (bxx >= 512) {
        // ---- CSR fill ----
        int i = (bxx - 512) * 256 + tid;   // [0, BB*(EG+EA))
        if (i < BB * EG) {
            int b = i >> 16, e = i & (EG - 1);
            const int* ei = ei_all + (size_t)b * 2 * EG;
            int s = ei[e], d = ei[EG + e];
            int p = atomicAdd(&curG[b * ME + d], 1);
            int2 v;
            v.x = t2e_all[(b << 14) + s];
            v.y = __float_as_int(dinv[b * ME + s]);
            csrG[(size_t)b * EG + p] = v;
        } else {
            int j = i - BB * EG;
            int b = j >> 16;
            int p = atomicAdd(&curA[b * NT + ed_all[j]], 1);
            int2 v;
            v.x = es_all[j];
            v.y = ed_all[j];
            csrA[(size_t)b * EA + p] = v;
        }
        return;
    }

    // ---- token GEMM ----
    int lane = tid & 63;
    int w = tid >> 6;
    long bm = (long)(bxx >> 1) * 64;
    int bcol = (bxx & 1) * 320;
    const unsigned short* Bblk = BtT + (long)bcol * DD;

    f32x4 acc[4][5] = {};

    for (int k0 = 0; k0 < DD; k0 += 32) {
        {
            int s = tid;
            int r = s >> 2;
            int gc = ((s & 3) ^ ((s >> 3) & 3)) * 8;
            __builtin_amdgcn_global_load_lds(
                (const __attribute__((address_space(1))) unsigned int*)(A + (bm + r) * DD + k0 + gc),
                (__attribute__((address_space(3))) unsigned int*)(As + s * 8), 16, 0, 0);
        }
#pragma unroll
        for (int i = 0; i < 5; ++i) {
            int s = tid + i * 256;
            int r = s >> 2;
            int gc = ((s & 3) ^ ((s >> 3) & 3)) * 8;
            __builtin_amdgcn_global_load_lds(
                (const __attribute__((address_space(1))) unsigned int*)(Bblk + (long)r * DD + k0 + gc),
                (__attribute__((address_space(3))) unsigned int*)(Bs + s * 8), 16, 0, 0);
        }
        __syncthreads();

        int cq = lane >> 4;
        bf16x8 af[4];
#pragma unroll
        for (int rb = 0; rb < 4; ++rb) {
            int r = rb * 16 + (lane & 15);
            af[rb] = *(const bf16x8*)&As[(r * 4 + (cq ^ ((r >> 1) & 3))) * 8];
        }
#pragma unroll
        for (int cb = 0; cb < 5; ++cb) {
            int r = w * 80 + cb * 16 + (lane & 15);
            bf16x8 bf = *(const bf16x8*)&Bs[(r * 4 + (cq ^ ((r >> 1) & 3))) * 8];
#pragma unroll
            for (int rb = 0; rb < 4; ++rb)
                acc[rb][cb] = __builtin_amdgcn_mfma_f32_16x16x32_bf16(af[rb], bf, acc[rb][cb], 0, 0, 0);
        }
        __syncthreads();
    }

#pragma unroll
    for (int rb = 0; rb < 4; ++rb) {
        long row0 = bm + rb * 16 + ((lane >> 4) << 2);
#pragma unroll
        for (int cb = 0; cb < 5; ++cb) {
            int col = bcol + w * 80 + cb * 16 + (lane & 15);
            float bv = bias640[col];
            if (col < 512) {
#pragma unroll
                for (int r = 0; r < 4; ++r)
                    Xg[(row0 + r) * DD + col] = f2bf(acc[rb][cb][r] + bv);
            } else if (col < 576) {
#pragma unroll
                for (int r = 0; r < 4; ++r)
                    Xk[(row0 + r) * DKK + (col - 512)] = f2bf(acc[rb][cb][r] + bv);
            } else {
#pragma unroll
                for (int r = 0; r < 4; ++r)
                    qmatb[(row0 + r) * DKK + (col - 576)] = f2bf(acc[rb][cb][r] + bv);
            }
        }
    }
}

// ---------------- GCN aggregation: one wave per (b,m), 4-deep main + clamped-4 tail ----------------
// XCD-batch swizzle: blocks of batch b land on XCDs {2b, 2b+1} (blockIdx%8 round-robin),
// so each XCD's L2 holds only that batch's Xg+Xk (~4.7 MB).
__global__ __launch_bounds__(256) void k_gcn_gather(
    const unsigned short* __restrict__ Xg, const unsigned short* __restrict__ Xk,
    const int* __restrict__ t2e_all, const float* __restrict__ dinv,
    const int* __restrict__ offsG, const int2* __restrict__ csrG,
    const float* __restrict__ biasG,
    unsigned short* __restrict__ eeb, unsigned short* __restrict__ kmatb)
{
    int w = threadIdx.x >> 6;
    int lane = threadIdx.x & 63;
    int bx = blockIdx.x;                   // [0, 16384)
    int b = (bx & 7) >> 1;                 // batch -> XCD pair
    int half = bx & 1;
    int idx = bx >> 3;                     // [0, 2048)
    int m = (half * 2048 + idx) * 4 + w;   // [0, 16384)
    int mg = (b << 14) + m;
    const int* offs = offsG + b * (ME + 1);
    const int2* csr = csrG + (size_t)b * EG;
    const unsigned short* gl = Xg + (((long)b * NT) << 9) + lane * 8;
    const unsigned short* kl = Xk + ((long)b * NT) * DKK + lane;

    float dm = dinv[mg];
    int self = t2e_all[mg];
    uint4 vself = *(const uint4*)(gl + ((long)self << 9));
    float kself = bf2f(kl[(long)self * DKK]);

    float a[8] = {0, 0, 0, 0, 0, 0, 0, 0};
    float ak = 0.0f;
    int p = offs[m], end = offs[m + 1];
    for (; p + 4 <= end; p += 4) {
        int2 e0 = csr[p], e1 = csr[p + 1], e2 = csr[p + 2], e3 = csr[p + 3];
        uint4 r0 = *(const uint4*)(gl + ((long)e0.x << 9));
        uint4 r1 = *(const uint4*)(gl + ((long)e1.x << 9));
        uint4 r2 = *(const uint4*)(gl + ((long)e2.x << 9));
        uint4 r3 = *(const uint4*)(gl + ((long)e3.x << 9));
        float k0 = bf2f(kl[(long)e0.x * DKK]);
        float k1 = bf2f(kl[(long)e1.x * DKK]);
        float k2 = bf2f(kl[(long)e2.x * DKK]);
        float k3 = bf2f(kl[(long)e3.x * DKK]);
        float w0 = __int_as_float(e0.y), w1 = __int_as_float(e1.y);
        float w2 = __int_as_float(e2.y), w3 = __int_as_float(e3.y);
        acc8(a, r0, w0); ak += w0 * k0;
        acc8(a, r1, w1); ak += w1 * k1;
        acc8(a, r2, w2); ak += w2 * k2;
        acc8(a, r3, w3); ak += w3 * k3;
    }
    if (p < end) {
        // branch-free clamped tail: keeps 4 loads in flight, zero-weights the pad slots
        int e1m = end - 1;
        int i1 = min(p + 1, e1m), i2 = min(p + 2, e1m), i3 = min(p + 3, e1m);
        int2 e0 = csr[p], e1 = csr[i1], e2 = csr[i2], e3 = csr[i3];
        uint4 r0 = *(const uint4*)(gl + ((long)e0.x << 9));
        uint4 r1 = *(const uint4*)(gl + ((long)e1.x << 9));
        uint4 r2 = *(const uint4*)(gl + ((long)e2.x << 9));
        uint4 r3 = *(const uint4*)(gl + ((long)e3.x << 9));
        float k0 = bf2f(kl[(long)e0.x * DKK]);
        float k1 = bf2f(kl[(long)e1.x * DKK]);
        float k2 = bf2f(kl[(long)e2.x * DKK]);
        float k3 = bf2f(kl[(long)e3.x * DKK]);
        float w0 = __int_as_float(e0.y);
        float w1 = (p + 1 < end) ? __int_as_float(e1.y) : 0.0f;
        float w2 = (p + 2 < end) ? __int_as_float(e2.y) : 0.0f;
        float w3 = (p + 3 < end) ? __int_as_float(e3.y) : 0.0f;
        acc8(a, r0, w0); ak += w0 * k0;
        acc8(a, r1, w1); ak += w1 * k1;
        acc8(a, r2, w2); ak += w2 * k2;
        acc8(a, r3, w3); ak += w3 * k3;
    }
    acc8(a, vself, dm);
    ak += dm * kself;

    const float* bg = biasG + lane * 8;
    float4 b0 = *(const float4*)bg;
    float4 b1 = *(const float4*)(bg + 4);
    a[0] = dm * a[0] + b0.x; a[1] = dm * a[1] + b0.y;
    a[2] = dm * a[2] + b0.z; a[3] = dm * a[3] + b0.w;
    a[4] = dm * a[4] + b1.x; a[5] = dm * a[5] + b1.y;
    a[6] = dm * a[6] + b1.z; a[7] = dm * a[7] + b1.w;
    *(uint4*)(eeb + ((long)mg << 9) + lane * 8) = pack8(a);
    kmatb[(long)mg * DKK + lane] = f2bf(dm * ak + biasG[512 + lane]);
}

// ---------------- attention dots: one thread per CSR position, XCD-batch swizzle ----------------
// writes fused (src, exp-weight-bits) stream so the gather loop issues ONE 8B load per edge
__global__ void k_dots(const unsigned short* __restrict__ kmatb,
                       const unsigned short* __restrict__ qmatb,
                       const int2* __restrict__ csrA, int2* __restrict__ swbuf) {
    int bx = blockIdx.x;                   // [0, 1024)
    int b = (bx & 7) >> 1;                 // batch -> XCD pair (kmatb+qmatb L2-resident)
    int half = bx & 1;
    int idx = bx >> 3;                     // [0, 128)
    int p = (b << 16) + (half * 128 + idx) * 256 + threadIdx.x;
    int2 sd = csrA[p];
    const uint4* kr = (const uint4*)(kmatb + ((long)(b * ME + sd.x) << 6));
    const uint4* qr = (const uint4*)(qmatb + ((long)(b * NT + sd.y) << 6));
    float dot = 0.0f;
#pragma unroll
    for (int j = 0; j < 8; ++j) {
        uint4 kv = kr[j];
        uint4 qv = qr[j];
        dot += __uint_as_float(kv.x << 16) * __uint_as_float(qv.x << 16)
             + __uint_as_float(kv.x & 0xffff0000u) * __uint_as_float(qv.x & 0xffff0000u)
             + __uint_as_float(kv.y << 16) * __uint_as_float(qv.y << 16)
             + __uint_as_float(kv.y & 0xffff0000u) * __uint_as_float(qv.y & 0xffff0000u)
             + __uint_as_float(kv.z << 16) * __uint_as_float(qv.z << 16)
             + __uint_as_float(kv.z & 0xffff0000u) * __uint_as_float(qv.z & 0xffff0000u)
             + __uint_as_float(kv.w << 16) * __uint_as_float(qv.w << 16)
             + __uint_as_float(kv.w & 0xffff0000u) * __uint_as_float(qv.w & 0xffff0000u);
    }
    int2 o;
    o.x = sd.x;
    o.y = __float_as_int(expf(dot * 0.125f));  // /sqrt(64); softmax max-shift is exact no-op
    swbuf[p] = o;
}

// ---------------- attention aggregation: one wave per (b,n), 8-deep ILP ----------------
// XCD-batch swizzle: batch b -> XCDs {2b,2b+1}; each XCD pair's L2 (8 MB) then serves only
// that batch's eeb (16.8 MB) -> random re-reads partially L2-absorbed.
__global__ __launch_bounds__(256) void k_att_gather(
    const unsigned short* __restrict__ eeb, const int2* __restrict__ swbuf,
    const int* __restrict__ offsA,
    const float* __restrict__ t_all, const float* __restrict__ ga,
    float* __restrict__ out, unsigned short* __restrict__ nb)
{
    int w = threadIdx.x >> 6;
    int lane = threadIdx.x & 63;
    int bx = blockIdx.x;                   // [0, 4096)
    int b = (bx & 7) >> 1;                 // batch -> XCD pair
    int half = bx & 1;
    int idx = bx >> 3;                     // [0, 512)
    int n = (half * 512 + idx) * 4 + w;    // [0, 4096)
    int ng = (b << 12) + n;
    const int* offs = offsA + b * (NT + 1);
    const int2* swb = swbuf + (size_t)b * EA;
    const unsigned short* el = eeb + (((size_t)b * ME) << 9) + lane * 8;

    float a[8] = {0, 0, 0, 0, 0, 0, 0, 0};
    float den = 0.0f;
    int p = offs[n], end = offs[n + 1];
    for (; p + 8 <= end; p += 8) {
        int2 e0 = swb[p],     e1 = swb[p + 1], e2 = swb[p + 2], e3 = swb[p + 3];
        int2 e4 = swb[p + 4], e5 = swb[p + 5], e6 = swb[p + 6], e7 = swb[p + 7];
        uint4 r0 = *(const uint4*)(el + ((long)e0.x << 9));
        uint4 r1 = *(const uint4*)(el + ((long)e1.x << 9));
        uint4 r2 = *(const uint4*)(el + ((long)e2.x << 9));
        uint4 r3 = *(const uint4*)(el + ((long)e3.x << 9));
        uint4 r4 = *(const uint4*)(el + ((long)e4.x << 9));
        uint4 r5 = *(const uint4*)(el + ((long)e5.x << 9));
        uint4 r6 = *(const uint4*)(el + ((long)e6.x << 9));
        uint4 r7 = *(const uint4*)(el + ((long)e7.x << 9));
        float w0 = __int_as_float(e0.y), w1 = __int_as_float(e1.y);
        float w2 = __int_as_float(e2.y), w3 = __int_as_float(e3.y);
        float w4 = __int_as_float(e4.y), w5 = __int_as_float(e5.y);
        float w6 = __int_as_float(e6.y), w7 = __int_as_float(e7.y);
        den += (w0 + w1 + w2 + w3) + (w4 + w5 + w6 + w7);
        acc8(a, r0, w0);
        acc8(a, r1, w1);
        acc8(a, r2, w2);
        acc8(a, r3, w3);
        acc8(a, r4, w4);
        acc8(a, r5, w5);
        acc8(a, r6, w6);
        acc8(a, r7, w7);
    }
    if (p < end) {
        // branch-free clamped tail: pad slots re-read row end-1 (L1 hit) with weight 0
        int e1m = end - 1;
        int2 e0 = swb[p];
        int2 e1 = swb[min(p + 1, e1m)];
        int2 e2 = swb[min(p + 2, e1m)];
        int2 e3 = swb[min(p + 3, e1m)];
        int2 e4 = swb[min(p + 4, e1m)];
        int2 e5 = swb[min(p + 5, e1m)];
        int2 e6 = swb[min(p + 6, e1m)];
        int2 e7 = swb[min(p + 7, e1m)];
        uint4 r0 = *(const uint4*)(el + ((long)e0.x << 9));
        uint4 r1 = *(const uint4*)(el + ((long)e1.x << 9));
        uint4 r2 = *(const uint4*)(el + ((long)e2.x << 9));
        uint4 r3 = *(const uint4*)(el + ((long)e3.x << 9));
        uint4 r4 = *(const uint4*)(el + ((long)e4.x << 9));
        uint4 r5 = *(const uint4*)(el + ((long)e5.x << 9));
        uint4 r6 = *(const uint4*)(el + ((long)e6.x << 9));
        uint4 r7 = *(const uint4*)(el + ((long)e7.x << 9));
        float w0 = __int_as_float(e0.y);
        float w1 = (p + 1 < end) ? __int_as_float(e1.y) : 0.0f;
        float w2 = (p + 2 < end) ? __int_as_float(e2.y) : 0.0f;
        float w3 = (p + 3 < end) ? __int_as_float(e3.y) : 0.0f;
        float w4 = (p + 4 < end) ? __int_as_float(e4.y) : 0.0f;
        float w5 = (p + 5 < end) ? __int_as_float(e5.y) : 0.0f;
        float w6 = (p + 6 < end) ? __int_as_float(e6.y) : 0.0f;
        float w7 = (p + 7 < end) ? __int_as_float(e7.y) : 0.0f;
        den += (w0 + w1 + w2 + w3) + (w4 + w5 + w6 + w7);
        acc8(a, r0, w0);
        acc8(a, r1, w1);
        acc8(a, r2, w2);
        acc8(a, r3, w3);
        acc8(a, r4, w4);
        acc8(a, r5, w5);
        acc8(a, r6, w6);
        acc8(a, r7, w7);
    }
    float g = tanhf(ga[0]);
    float inv = den > 0.0f ? g / den : 0.0f;
    const float* tr = t_all + ((long)ng << 9) + lane * 8;
    float4 t0 = *(const float4*)tr;
    float4 t1 = *(const float4*)(tr + 4);
    float o[8];
    o[0] = t0.x + inv * a[0]; o[1] = t0.y + inv * a[1];
    o[2] = t0.z + inv * a[2]; o[3] = t0.w + inv * a[3];
    o[4] = t1.x + inv * a[4]; o[5] = t1.y + inv * a[5];
    o[6] = t1.z + inv * a[6]; o[7] = t1.w + inv * a[7];
    float* op = out + ((long)ng << 9) + lane * 8;
    *(float4*)op = make_float4(o[0], o[1], o[2], o[3]);
    *(float4*)(op + 4) = make_float4(o[4], o[5], o[6], o[7]);
    *(uint4*)(nb + ((long)ng << 9) + lane * 8) = pack8(o);
}

// ---------------- final linear: 128-row x 256-col blocks, XOR-swizzled LDS ----------------
// Cf += tanh(gs[0]) * (A @ Bt^T + bias)
__global__ __launch_bounds__(256, 2) void gemm_final(
    const unsigned short* __restrict__ A, const unsigned short* __restrict__ Bt,
    const float* __restrict__ bias, float* __restrict__ Cf, const float* __restrict__ gs)
{
    constexpr int CB = 8;
    constexpr int BROWS = 2 * CB * 16;      // 256
    __shared__ short As[128 * 32];
    __shared__ short Bs[BROWS * 32];
    int tid = threadIdx.x;
    int lane = tid & 63;
    int w = tid >> 6;
    int wm = w >> 1, wn = w & 1;
    long bm = (long)blockIdx.x * 128;
    int bcol = blockIdx.y * BROWS;
    const unsigned short* Bblk = Bt + (long)bcol * DD;

    f32x4 acc[4][CB] = {};

    for (int k0 = 0; k0 < DD; k0 += 32) {
#pragma unroll
        for (int i = 0; i < 2; ++i) {
            int s = tid + i * 256;
            int r = s >> 2;
            int gc = ((s & 3) ^ ((s >> 3) & 3)) * 8;
            __builtin_amdgcn_global_load_lds(
                (const __attribute__((address_space(1))) unsigned int*)(A + (bm + r) * DD + k0 + gc),
                (__attribute__((address_space(3))) unsigned int*)(As + s * 8), 16, 0, 0);
        }
#pragma unroll
        for (int i = 0; i < CB / 2; ++i) {
            int s = tid + i * 256;
            int r = s >> 2;
            int gc = ((s & 3) ^ ((s >> 3) & 3)) * 8;
            __builtin_amdgcn_global_load_lds(
                (const __attribute__((address_space(1))) unsigned int*)(Bblk + (long)r * DD + k0 + gc),
                (__attribute__((address_space(3))) unsigned int*)(Bs + s * 8), 16, 0, 0);
        }
        __syncthreads();

        int cq = lane >> 4;
        bf16x8 af[4];
#pragma unroll
        for (int rb = 0; rb < 4; ++rb) {
            int r = wm * 64 + rb * 16 + (lane & 15);
            af[rb] = *(const bf16x8*)&As[(r * 4 + (cq ^ ((r >> 1) & 3))) * 8];
        }
#pragma unroll
        for (int cb = 0; cb < CB; ++cb) {
            int r = wn * (CB * 16) + cb * 16 + (lane & 15);
            bf16x8 bf = *(const bf16x8*)&Bs[(r * 4 + (cq ^ ((r >> 1) & 3))) * 8];
#pragma unroll
            for (int rb = 0; rb < 4; ++rb)
                acc[rb][cb] = __builtin_amdgcn_mfma_f32_16x16x32_bf16(af[rb], bf, acc[rb][cb], 0, 0, 0);
        }
        __syncthreads();
    }

    float g = tanhf(gs[0]);
#pragma unroll
    for (int rb = 0; rb < 4; ++rb) {
        long row0 = bm + wm * 64 + rb * 16 + ((lane >> 4) << 2);
#pragma unroll
        for (int cb = 0; cb < CB; ++cb) {
            int col = bcol + wn * (CB * 16) + cb * 16 + (lane & 15);
            float bv = bias[col];
#pragma unroll
            for (int r = 0; r < 4; ++r)
                Cf[(row0 + r) * DD + col] += g * (acc[rb][cb][r] + bv);
        }
    }
}

extern "C" void kernel_launch(void* const* d_in, const int* in_sizes, int n_in,
                              void* d_out, int out_size, void* d_ws, size_t ws_size,
                              hipStream_t stream) {
    const float* t_all   = (const float*)d_in[0];
    const int*   t2e_all = (const int*)d_in[1];
    const int*   ei_all  = (const int*)d_in[2];
    const int*   es_all  = (const int*)d_in[3];
    const int*   ed_all  = (const int*)d_in[4];
    const float* Wgnn    = (const float*)d_in[5];
    const float* bgnn    = (const float*)d_in[6];
    const float* Wk      = (const float*)d_in[7];
    const float* bk      = (const float*)d_in[8];
    const float* Wq      = (const float*)d_in[9];
    const float* bq      = (const float*)d_in[10];
    const float* Wl      = (const float*)d_in[11];
    const float* bl      = (const float*)d_in[12];
    const float* ga      = (const float*)d_in[13];
    const float* gb      = (const float*)d_in[14];
    float* out = (float*)d_out;

    // workspace (~145 MB of 256 MiB)
    char* wsb = (char*)d_ws;
    size_t off = 0;
    unsigned short* eeb   = (unsigned short*)(wsb + off); off += (size_t)BB * ME * DD * 2;  // 67.1 MB
    unsigned short* tb    = (unsigned short*)(wsb + off); off += (size_t)BB * NT * DD * 2;  // 16.8 MB
    unsigned short* Xg    = (unsigned short*)(wsb + off); off += (size_t)BB * NT * DD * 2;  // 16.8 MB
    unsigned short* nb    = (unsigned short*)(wsb + off); off += (size_t)BB * NT * DD * 2;  // 16.8 MB
    unsigned short* Xk    = (unsigned short*)(wsb + off); off += (size_t)BB * NT * DKK * 2; // 2.1 MB
    unsigned short* qmatb = (unsigned short*)(wsb + off); off += (size_t)BB * NT * DKK * 2; // 2.1 MB
    unsigned short* kmatb = (unsigned short*)(wsb + off); off += (size_t)BB * ME * DKK * 2; // 8.4 MB
    unsigned short* BtT   = (unsigned short*)(wsb + off); off += (size_t)640 * DD * 2;
    unsigned short* Wlt   = (unsigned short*)(wsb + off); off += (size_t)DD * DD * 2;
    float* biasG   = (float*)(wsb + off); off += 576 * 4;
    float* bias640 = (float*)(wsb + off); off += 640 * 4;
    float* dinv  = (float*)(wsb + off); off += (size_t)BB * ME * 4;
    int2* swbuf  = (int2*)(wsb + off); off += (size_t)BB * EA * 8;   // fused (src, exp-weight)
    int* cntG  = (int*)(wsb + off); off += (size_t)BB * ME * 4;   // cntG+cntA contiguous
    int* cntA  = (int*)(wsb + off); off += (size_t)BB * NT * 4;
    int* offsG = (int*)(wsb + off); off += (size_t)BB * (ME + 1) * 4;
    int* curG  = (int*)(wsb + off); off += (size_t)BB * ME * 4;
    int2* csrG = (int2*)(wsb + off); off += (size_t)BB * EG * 8;
    int* offsA = (int*)(wsb + off); off += (size_t)BB * (NT + 1) * 4;
    int* curA  = (int*)(wsb + off); off += (size_t)BB * NT * 4;
    int2* csrA = (int2*)(wsb + off); off += (size_t)BB * EA * 8;

    // ---- fused prep: wtT | bias | cast | hist (after counter memset) ----
    hipMemsetAsync(cntG, 0, (size_t)BB * (ME + NT) * 4, stream);
    k_prep<<<PREP_HIST, 256, 0, stream>>>(
        Wgnn, Wk, Wq, Wl, bgnn, bk, bq, t_all, ei_all, ed_all,
        BtT, Wlt, biasG, bias640, tb, cntG, cntA);

    // ---- scan ----
    k_scan2<<<2 * BB, 1024, 0, stream>>>(cntG, offsG, curG, dinv, cntA, offsA, curA);

    // ---- fused: token GEMM + CSR fill (independent; overlap in one launch) ----
    k_fill_token<<<512 + 2048, 256, 0, stream>>>(
        ei_all, es_all, ed_all, t2e_all, dinv, curG, csrG, curA, csrA,
        tb, BtT, bias640, Xg, Xk, qmatb);

    // ---- GCN aggregation in projected space -> eeb, kmatb directly ----
    k_gcn_gather<<<(BB * ME * 64) / 256, 256, 0, stream>>>(
        Xg, Xk, t2e_all, dinv, offsG, csrG, biasG, eeb, kmatb);

    // ---- attention ----
    k_dots<<<(BB * EA) / 256, 256, 0, stream>>>(kmatb, qmatb, csrA, swbuf);
    k_att_gather<<<(BB * NT * 64) / 256, 256, 0, stream>>>(
        eeb, swbuf, offsA, t_all, ga, out, nb);

    // ---- final: out += tanh(gb) * (nb @ Wl + bl) ----
    gemm_final<<<dim3((BB * NT) / 128, 2), 256, 0, stream>>>(nb, Wlt, bl, out, gb);
}